// Round 14
// baseline (131.328 us; speedup 1.0000x reference)
//
#include <hip/hip_runtime.h>
#include <hip/hip_bf16.h>
#include <stdint.h>

typedef float  f32x4 __attribute__((ext_vector_type(4)));
typedef short  s16x8 __attribute__((ext_vector_type(8)));
typedef short  s16x4 __attribute__((ext_vector_type(4)));
typedef int    i32x4 __attribute__((ext_vector_type(4)));

#define DI __device__ __forceinline__

constexpr int Bb = 2, Tt = 2048, Ff = 1024, Hh = 16, Dk = 64;
constexpr int Mm = Bb * Tt;  // 4096 rows
constexpr float LOG2E = 1.44269504088896340736f;

DI ushort f2bf(float f) {  // round-to-nearest-even f32 -> bf16 (raw bits)
  unsigned u = __float_as_uint(f);
  unsigned r = (u + 0x7fffu + ((u >> 16) & 1u)) >> 16;
  return (ushort)r;
}

DI int cvt_pk_bf16(float lo, float hi) {  // packed f32x2 -> bf16x2 (v_cvt_pk_bf16_f32)
  __hip_bfloat162 t = __float22bfloat162_rn(make_float2(lo, hi));
  int w;
  __builtin_memcpy(&w, &t, 4);
  return w;
}

DI s16x8 pack8(const float4& a, const float4& b) {  // 8 f32 -> 8 bf16 (RNE, == old cvt3 rounding)
  i32x4 w;
  w[0] = cvt_pk_bf16(a.x, a.y); w[1] = cvt_pk_bf16(a.z, a.w);
  w[2] = cvt_pk_bf16(b.x, b.y); w[3] = cvt_pk_bf16(b.z, b.w);
  return __builtin_bit_cast(s16x8, w);
}

DI void gload16(const void* g, void* l) {  // async global->LDS, 16B/lane, dst = wave-uniform base + lane*16
  __builtin_amdgcn_global_load_lds(
      (__attribute__((address_space(1))) void*)g,
      (__attribute__((address_space(3))) void*)l, 16, 0, 0);
}

DI void wait_vm4() { asm volatile("s_waitcnt vmcnt(4)" ::: "memory"); }
DI void wait_vm6() { asm volatile("s_waitcnt vmcnt(6)" ::: "memory"); }
DI void wait_vm0() { asm volatile("s_waitcnt vmcnt(0)" ::: "memory"); }
DI void wait_lgkm0() { asm volatile("s_waitcnt lgkmcnt(0)" ::: "memory"); }

// ---------------- merged prep: wtrans (1024 blk) + maskflag (2048 blk) ----------------
__global__ __launch_bounds__(256) void prep_kernel(
    const float* __restrict__ W0, const float* __restrict__ W1,
    const float* __restrict__ W2, const float* __restrict__ W3,
    ushort* __restrict__ Wt0, ushort* __restrict__ Wt1,
    ushort* __restrict__ Wt2, ushort* __restrict__ Wt3,
    const int* __restrict__ mask, int* __restrict__ flags) {
  const int bid = blockIdx.x;
  const int t = threadIdx.x;
  if (bid < 1024) {
    // --- wtrans: W[k][n] f32 -> Wt[n][k] bf16 ---
    const int z = bid >> 8, bx = bid & 15, by = (bid >> 4) & 15;
    const float* W; ushort* Wt;
    switch (z) {
      case 0: W = W0; Wt = Wt0; break;
      case 1: W = W1; Wt = Wt1; break;
      case 2: W = W2; Wt = Wt2; break;
      default: W = W3; Wt = Wt3; break;
    }
    __shared__ float tile[64][65];
    const int k0 = by * 64, n0 = bx * 64;
    const int r = t >> 4, c4 = (t & 15) * 4;
#pragma unroll
    for (int i = 0; i < 4; i++) {
      const int row = r + i * 16;
      const float4 v = *(const float4*)(W + (size_t)(k0 + row) * Ff + n0 + c4);
      tile[row][c4] = v.x; tile[row][c4 + 1] = v.y; tile[row][c4 + 2] = v.z; tile[row][c4 + 3] = v.w;
    }
    __syncthreads();
#pragma unroll
    for (int i = 0; i < 4; i++) {
      const int n = r + i * 16;
      s16x4 o;
#pragma unroll
      for (int j = 0; j < 4; j++) o[j] = (short)f2bf(tile[c4 + j][n]);
      *(s16x4*)(Wt + (size_t)(n0 + n) * Ff + k0 + c4) = o;
    }
  } else {
    // --- maskflag: flag=1 iff whole 64x64 tile > 0 ---
    const int mb = bid - 1024;
    const int kb = mb & 31, qb = (mb >> 5) & 31, bz = mb >> 10;
    __shared__ int s;
    if (t == 0) s = 1;
    __syncthreads();
    int ok = 1;
#pragma unroll
    for (int i = 0; i < 4; i++) {
      const int row = qb * 64 + (t >> 4) + i * 16;
      const int4 v = *(const int4*)(mask + ((size_t)bz * Tt + row) * Tt + kb * 64 + (t & 15) * 4);
      ok &= (v.x > 0) & (v.y > 0) & (v.z > 0) & (v.w > 0);
    }
    atomicAnd(&s, ok);
    __syncthreads();
    if (t == 0) flags[(bz * 32 + qb) * 32 + kb] = s;
  }
}

// ---------------- bf16 GEMM (bf16 A via gload), BK=32 ring-3, chunk-XOR swizzled ----------------
// Chunk c of row r stored at slot s = c^((r>>1)&3): per 16-lane phase the b128 reads tile
// banks 0-15 / 16-31 at 2 lanes/quad = 2-way (free). 0 conflicts measured (round 12).
DI void gemm_core(const ushort* __restrict__ A, const ushort* __restrict__ Bt,
                  const float* __restrict__ bias, float* __restrict__ Cout, int m0, int n0) {
  __shared__ ushort Ads[3][128 * 32];  // 24 KB ring
  __shared__ ushort Bds[3][128 * 32];  // 24 KB ring
  const int tid = threadIdx.x, lane = tid & 63, w = tid >> 6;
  const int wr = w >> 1, wc = w & 1;
  const int g = lane >> 4, ln = lane & 15;
  const int strow = tid >> 2;        // staging row 0..63 (also row+64)
  const int sc = tid & 3;            // linear 16B slot within row
  const int sx = (strow >> 1) & 3;   // row swizzle key (same for strow and strow+64)
  const int swch = ((sc ^ sx) * 8);  // pre-swizzled SOURCE chunk offset (ushorts)

  const ushort* Asrc0 = A + (size_t)(m0 + strow) * Ff + swch;
  const ushort* Asrc1 = A + (size_t)(m0 + 64 + strow) * Ff + swch;
  const ushort* Bsrc0 = Bt + (size_t)(n0 + strow) * Ff + swch;
  const ushort* Bsrc1 = Bt + (size_t)(n0 + 64 + strow) * Ff + swch;
  const int dst0 = strow * 32 + sc * 8;          // linear dst = base + lane*16B
  const int dst1 = (64 + strow) * 32 + sc * 8;

  f32x4 acc[4][4];
#pragma unroll
  for (int m = 0; m < 4; m++)
#pragma unroll
    for (int n = 0; n < 4; n++) acc[m][n] = (f32x4){0.f, 0.f, 0.f, 0.f};

  auto stage = [&](int t, int slot) {
    const int k0 = t * 32;
    gload16(Asrc0 + k0, Ads[slot] + dst0);
    gload16(Asrc1 + k0, Ads[slot] + dst1);
    gload16(Bsrc0 + k0, Bds[slot] + dst0);
    gload16(Bsrc1 + k0, Bds[slot] + dst1);
  };

  stage(0, 0);
  stage(1, 1);

  int rs = 0, ws = 2;
  for (int t = 0; t < 32; ++t) {
    if (t < 31) wait_vm4(); else wait_vm0();
    __builtin_amdgcn_s_barrier();
    __builtin_amdgcn_sched_barrier(0);
    if (t < 30) stage(t + 2, ws);
    const ushort* As = Ads[rs];
    const ushort* Bs = Bds[rs];
    s16x8 af[4], bf[4];
#pragma unroll
    for (int m = 0; m < 4; m++) {
      const int ra = wr * 64 + m * 16 + ln;
      af[m] = *(const s16x8*)(As + ra * 32 + ((g ^ ((ra >> 1) & 3)) * 8));
    }
#pragma unroll
    for (int n = 0; n < 4; n++) {
      const int rb = wc * 64 + n * 16 + ln;
      bf[n] = *(const s16x8*)(Bs + rb * 32 + ((g ^ ((rb >> 1) & 3)) * 8));
    }
    __builtin_amdgcn_s_setprio(1);
#pragma unroll
    for (int m = 0; m < 4; m++)
#pragma unroll
      for (int n = 0; n < 4; n++)
        acc[m][n] = __builtin_amdgcn_mfma_f32_16x16x32_bf16(af[m], bf[n], acc[m][n], 0, 0, 0);
    __builtin_amdgcn_s_setprio(0);
    rs = rs == 2 ? 0 : rs + 1;
    ws = ws == 2 ? 0 : ws + 1;
  }
#pragma unroll
  for (int m = 0; m < 4; m++) {
    const int r0 = m0 + wr * 64 + m * 16 + g * 4;
#pragma unroll
    for (int n = 0; n < 4; n++) {
      const int col = n0 + wc * 64 + n * 16 + ln;
      const float bv = bias[col];
#pragma unroll
      for (int r = 0; r < 4; r++)
        Cout[(size_t)(r0 + r) * Ff + col] = acc[m][n][r] + bv;
    }
  }
}

// ---------------- bf16 GEMM with F32 A (fused convert), BK=32 ring-3, swizzled ----------------
// Round-14: round-13's V-epilogue FIXED — the copy loop only wrote half the tile (j<4 covered
// 32 of 64 ushorts/thread; absmax 3.7e-2). Now j<8 (full tile) + an 8-ushort-chunk XOR swizzle
// (c8 ^= col&15) on BOTH quadrant-store and copy-read (rule #21) so the coalesced copy reads
// are 2-way instead of 16-way conflicted. Values/rounding identical to the scattered store.
DI void gemm_core_f32a(const float* __restrict__ A, const ushort* __restrict__ Bt,
                       const float* __restrict__ bias, void* __restrict__ Cout, float scale,
                       int mode, int m0, int n0) {
  __shared__ ushort smem[24576];  // 48 KB: A ring [0,12288), B ring [12288,24576); V-tile reuses [0,16384)
  ushort* AdsB = smem;
  ushort* BdsB = smem + 12288;
  const int tid = threadIdx.x, lane = tid & 63, w = tid >> 6;
  const int wr = w >> 1, wc = w & 1;
  const int g = lane >> 4, ln = lane & 15;
  const int strow = tid >> 2;
  const int sc = tid & 3;
  const int sx = (strow >> 1) & 3;   // same key for strow and strow+64
  const int stcf = sc * 8;           // this thread's OWN chunk (floats) — A loads stay coalesced

  const float*  Asrc0 = A + (size_t)(m0 + strow) * Ff + stcf;
  const float*  Asrc1 = A + (size_t)(m0 + 64 + strow) * Ff + stcf;
  const ushort* Bsrc0 = Bt + (size_t)(n0 + strow) * Ff + ((sc ^ sx) * 8);
  const ushort* Bsrc1 = Bt + (size_t)(n0 + 64 + strow) * Ff + ((sc ^ sx) * 8);
  const int dstA0 = strow * 32 + ((sc ^ sx) * 8);         // SWIZZLED ds_write slot
  const int dstA1 = (64 + strow) * 32 + ((sc ^ sx) * 8);
  const int dstB0 = strow * 32 + sc * 8;                  // linear gload dst (= base + lane*16B)
  const int dstB1 = (64 + strow) * 32 + sc * 8;

  float4 rA0a, rA0b, rA1a, rA1b;  // staged A for next tile (2 rows x 8 f32)
  auto loadA = [&](int t) {
    const float* p0 = Asrc0 + t * 32;
    const float* p1 = Asrc1 + t * 32;
    rA0a = *(const float4*)p0; rA0b = *(const float4*)(p0 + 4);
    rA1a = *(const float4*)p1; rA1b = *(const float4*)(p1 + 4);
  };
  auto writeA = [&](int slot) {
    *(s16x8*)(AdsB + slot * 4096 + dstA0) = pack8(rA0a, rA0b);
    *(s16x8*)(AdsB + slot * 4096 + dstA1) = pack8(rA1a, rA1b);
  };
  auto stageB = [&](int t, int slot) {
    const int k0 = t * 32;
    gload16(Bsrc0 + k0, BdsB + slot * 4096 + dstB0);
    gload16(Bsrc1 + k0, BdsB + slot * 4096 + dstB1);
  };

  f32x4 acc[4][4];
#pragma unroll
  for (int m = 0; m < 4; m++)
#pragma unroll
    for (int n = 0; n < 4; n++) acc[m][n] = (f32x4){0.f, 0.f, 0.f, 0.f};

  // prologue: A(0) regs -> LDS slot0 (compiler-waited); then A(1) regs; B(0),B(1) gloads.
  loadA(0);
  writeA(0);
  stageB(0, 0);   // older than the 6 newest below -> drained by first wait_vm6
  loadA(1);       // 4 loads
  stageB(1, 1);   // 2 gloads  => newest 6 = A(1)x4 + B(1)x2

  int rs = 0, ps = 1, ws = 2;
  for (int t = 0; t < 32; ++t) {
    if (t < 31) wait_vm6(); else wait_vm0();  // drains B(t) + older; leaves A(t+1),B(t+1)
    wait_lgkm0();                             // publish last iter's A ds_writes
    __builtin_amdgcn_s_barrier();
    __builtin_amdgcn_sched_barrier(0);
    if (t < 31) writeA(ps);                   // A(t+1) regs -> slot (t+1)%3 (auto-waited)
    if (t < 30) { loadA(t + 2); stageB(t + 2, ws); }  // exactly 6 VM ops
    const ushort* As = AdsB + rs * 4096;
    const ushort* Bs = BdsB + rs * 4096;
    s16x8 af[4], bf[4];
#pragma unroll
    for (int m = 0; m < 4; m++) {
      const int ra = wr * 64 + m * 16 + ln;
      af[m] = *(const s16x8*)(As + ra * 32 + ((g ^ ((ra >> 1) & 3)) * 8));
    }
#pragma unroll
    for (int n = 0; n < 4; n++) {
      const int rb = wc * 64 + n * 16 + ln;
      bf[n] = *(const s16x8*)(Bs + rb * 32 + ((g ^ ((rb >> 1) & 3)) * 8));
    }
    __builtin_amdgcn_s_setprio(1);
#pragma unroll
    for (int m = 0; m < 4; m++)
#pragma unroll
      for (int n = 0; n < 4; n++)
        acc[m][n] = __builtin_amdgcn_mfma_f32_16x16x32_bf16(af[m], bf[n], acc[m][n], 0, 0, 0);
    __builtin_amdgcn_s_setprio(0);
    rs = rs == 2 ? 0 : rs + 1;
    ps = ps == 2 ? 0 : ps + 1;
    ws = ws == 2 ? 0 : ws + 1;
  }
  if (mode == 2) {
    // --- V epilogue: LDS-coalesced store (round-14, fixed) ---
    // Logical tile: Vl[col 0..127][p 0..127], p = wr*64 + pbase(m,g) + r (pi-permuted position).
    // Physical: 8-ushort chunk c8 = p>>3 stored at c8 ^ (col&15) (write+read both swizzled).
    __syncthreads();  // main-loop LDS dead (last iter has no trailing barrier)
    ushort* Vl = smem;  // 16384 ushorts = 32 KB
#pragma unroll
    for (int m = 0; m < 4; m++) {
#pragma unroll
      for (int n = 0; n < 4; n++) {
        const int col_l = wc * 64 + n * 16 + ln;
        const float bv = bias[n0 + col_l];
        const int x = m * 16 + g * 4;  // (row & 63) at r=0
        const int pbase = (x & 0x20) | ((x & 0x0C) << 1) | ((x & 0x10) >> 2);
        const int p = wr * 64 + pbase;                    // 0..127, multiple of 4
        const int addr = col_l * 128 + (((p >> 3) ^ (col_l & 15)) << 3) + (p & 7);
        s16x4 o4;
#pragma unroll
        for (int r = 0; r < 4; r++) o4[r] = (short)f2bf(acc[m][n][r] + bv);
        *(s16x4*)(Vl + addr) = o4;
      }
    }
    __syncthreads();
    const int bb = m0 >> 11, rbase = m0 & 2047;
    const int cl = tid >> 1, hf = tid & 1;
    ushort* dstg = (ushort*)Cout + ((size_t)bb * Ff + n0 + cl) * Tt + rbase + hf * 64;
#pragma unroll
    for (int j = 0; j < 8; j++) {                          // FULL 64 ushorts/thread (was j<4: bug)
      const int c8 = hf * 8 + j;                           // p = hf*64 + j*8
      const ushort* src8 = Vl + cl * 128 + ((c8 ^ (cl & 15)) << 3);
      *(s16x8*)(dstg + j * 8) = *(const s16x8*)src8;
    }
  } else {
#pragma unroll
    for (int m = 0; m < 4; m++) {
      const int r0 = m0 + wr * 64 + m * 16 + g * 4;
#pragma unroll
      for (int n = 0; n < 4; n++) {
        const int col = n0 + wc * 64 + n * 16 + ln;
        const float bv = bias[col];
#pragma unroll
        for (int r = 0; r < 4; r++)
          ((ushort*)Cout)[(size_t)(r0 + r) * Ff + col] = f2bf((acc[m][n][r] + bv) * scale);
      }
    }
  }
}

__global__ __launch_bounds__(256) void qkv_gemm_kernel(
    const float* __restrict__ Xq, const float* __restrict__ Xk, const float* __restrict__ Xv,
    const ushort* __restrict__ Wqt, const ushort* __restrict__ Wkt, const ushort* __restrict__ Wvt,
    const float* __restrict__ bq, const float* __restrict__ bk, const float* __restrict__ bv,
    ushort* __restrict__ Qb, ushort* __restrict__ Kb, ushort* __restrict__ Vpt) {
  // T1: XCD-chunked bijective block swizzle (768 blocks -> 96 contiguous per XCD)
  const int lin = blockIdx.x + 8 * blockIdx.y + 256 * blockIdx.z;
  const int work = (lin & 7) * 96 + (lin >> 3);
  const int z = work >> 8;
  const int r = work & 255;
  const int m0 = (r >> 3) * 128, n0 = (r & 7) * 128;
  const float* A = z == 0 ? Xq : (z == 1 ? Xk : Xv);
  const ushort* Wt = z == 0 ? Wqt : (z == 1 ? Wkt : Wvt);
  const float* bias = z == 0 ? bq : (z == 1 ? bk : bv);
  void* C = z == 0 ? (void*)Qb : (z == 1 ? (void*)Kb : (void*)Vpt);
  const float scale = z == 0 ? 0.125f * LOG2E : 1.0f;  // fold 1/sqrt(64) and log2(e) into Q
  gemm_core_f32a(A, Wt, bias, C, scale, z == 2 ? 2 : 1, m0, n0);
}

__global__ __launch_bounds__(256) void out_gemm_kernel(const ushort* __restrict__ AO,
                                                       const ushort* __restrict__ Wot,
                                                       const float* __restrict__ bo,
                                                       float* __restrict__ Out) {
  // T1: XCD-chunked bijective block swizzle (256 blocks -> 32 contiguous per XCD)
  const int lin = blockIdx.x + 8 * blockIdx.y;
  const int work = (lin & 7) * 32 + (lin >> 3);
  const int m0 = (work >> 3) * 128, n0 = (work & 7) * 128;
  gemm_core(AO, Wot, bo, Out, m0, n0);
}

// ---------------- flash attention (round-8 best: max-free exp2, QBLK=128, ring-4 pair sync) ----------------
// grid (qb=16, h=16, b=2), 256 thr (4 waves). BQ=128 (two 16-row groups/wave), BK=64, D=64.
// Ring-4 (64 KB LDS): per half-iter {compute 2 tiles -> __syncthreads -> stage next pair};
// each staged pair gets a full 2-tile compute phase to land; 16 barriers total.
// l on MFMA pipe via ones-B trick (acc reg r = l for q-row 4g+r).
__global__ __launch_bounds__(256) void flash_kernel(
    const ushort* __restrict__ Qb, const ushort* __restrict__ Kb, const ushort* __restrict__ Vpt,
    const int* __restrict__ flags, const int* __restrict__ mask, ushort* __restrict__ AO) {
  __shared__ ushort Ks[4][64 * 64];
  __shared__ ushort Vs[4][64 * 64];
  // T1: XCD-chunked bijective block swizzle (512 blocks -> 64 per XCD = 4 heads' KV, L2-fit)
  const int lin = blockIdx.x + 16 * (blockIdx.y + 16 * blockIdx.z);
  const int work = (lin & 7) * 64 + (lin >> 3);
  const int qb = work & 15, h = (work >> 4) & 15, b = work >> 8;
  const int tid = threadIdx.x, lane = tid & 63, w = tid >> 6;
  const int g = lane >> 4, ln = lane & 15;

  const ushort* Qg = Qb + ((size_t)b * Tt + qb * 128) * Ff + h * Dk;
  const ushort* Kg = Kb + ((size_t)b * Tt) * Ff + h * Dk;
  const ushort* Vg = Vpt + (size_t)(b * Ff + h * Dk) * Tt;  // rows d, stride Tt, cols pi-ordered

  const int srow = lane >> 3;
  const int swzch = ((lane & 7) ^ srow) * 8;  // inverse-swizzled source chunk (128B rows need XOR)

  // persistent staging source pointers (advance one PAIR of KV tiles per stage2)
  const ushort* ksrc0 = Kg + (size_t)(w * 16 + srow) * Ff + swzch;
  const ushort* ksrc1 = ksrc0 + (size_t)8 * Ff;
  const ushort* vsrc0 = Vg + (size_t)(w * 16 + srow) * Tt + swzch;
  const ushort* vsrc1 = vsrc0 + (size_t)8 * Tt;

  // Q fragments DIRECT from global (one-time read): qf{j}[c] = Q[j*64 + w*16+ln][c*32+g*8 ..+7]
  s16x8 qf0[2], qf1[2];
  {
    const ushort* Qrow0 = Qg + (size_t)(w * 16 + ln) * Ff;
    const ushort* Qrow1 = Qrow0 + (size_t)64 * Ff;
    qf0[0] = *(const s16x8*)(Qrow0 + g * 8);
    qf0[1] = *(const s16x8*)(Qrow0 + 32 + g * 8);
    qf1[0] = *(const s16x8*)(Qrow1 + g * 8);
    qf1[1] = *(const s16x8*)(Qrow1 + 32 + g * 8);
  }
  const int* flagrow0 = flags + (b * 32 + qb * 2) * 32;
  const int f0 = (lane < 32) ? flagrow0[lane] : 1;
  const int f1 = (lane < 32) ? flagrow0[32 + lane] : 1;

  // stage a PAIR of consecutive KV tiles into two slots, advance pointers by 2 tiles
  auto stage2 = [&](ushort* Kd0, ushort* Vd0, ushort* Kd1, ushort* Vd1) {
    const int r0 = w * 16;
    gload16(ksrc0, Kd0 + r0 * 64);
    gload16(ksrc1, Kd0 + (r0 + 8) * 64);
    gload16(vsrc0, Vd0 + r0 * 64);
    gload16(vsrc1, Vd0 + (r0 + 8) * 64);
    gload16(ksrc0 + (size_t)64 * Ff, Kd1 + r0 * 64);
    gload16(ksrc1 + (size_t)64 * Ff, Kd1 + (r0 + 8) * 64);
    gload16(vsrc0 + 64, Vd1 + r0 * 64);
    gload16(vsrc1 + 64, Vd1 + (r0 + 8) * 64);
    ksrc0 += (size_t)128 * Ff; ksrc1 += (size_t)128 * Ff;
    vsrc0 += 128; vsrc1 += 128;
  };

  // prologue: stage tiles 0..3 into slots 0..3, full drain once
  stage2(Ks[0], Vs[0], Ks[1], Vs[1]);
  stage2(Ks[2], Vs[2], Ks[3], Vs[3]);
  __syncthreads();
  const unsigned long long bm0 = __ballot(f0 == 0);
  const unsigned long long bm1 = __ballot(f1 == 0);

  // hoisted LDS read byte-offsets: rows i*16+ln, chunk c — shared by QK (K) and PV (V) reads
  int loff[4][2];
#pragma unroll
  for (int i = 0; i < 4; i++)
#pragma unroll
    for (int c = 0; c < 2; c++) {
      const int row = i * 16 + ln;
      loff[i][c] = row * 128 + ((c * 64 + g * 16) ^ ((row & 7) << 4));
    }
  const char* Kbase = (const char*)&Ks[0][0];
  const char* Vbase = (const char*)&Vs[0][0];

  s16x8 onesf;
#pragma unroll
  for (int j = 0; j < 8; ++j) onesf[j] = (short)0x3F80;  // bf16 1.0

  f32x4 accl0 = (f32x4){0.f, 0.f, 0.f, 0.f}, accl1 = (f32x4){0.f, 0.f, 0.f, 0.f};
  f32x4 o0[4], o1[4];
#pragma unroll
  for (int ds = 0; ds < 4; ds++) { o0[ds] = (f32x4){0.f, 0.f, 0.f, 0.f}; o1[ds] = (f32x4){0.f, 0.f, 0.f, 0.f}; }

  auto body = [&](int slot, int kt) {
    const char* Kc = Kbase + slot * 8192;
    const char* Vc = Vbase + slot * 8192;
    // --- S'^T = K * Q^T (log2 domain); each kf feeds BOTH q-groups ---
    f32x4 sf0[4], sf1[4];
    __builtin_amdgcn_s_setprio(1);
#pragma unroll
    for (int ks = 0; ks < 4; ++ks) {
      f32x4 a0 = (f32x4){0.f, 0.f, 0.f, 0.f};
      f32x4 a1 = (f32x4){0.f, 0.f, 0.f, 0.f};
#pragma unroll
      for (int c = 0; c < 2; c++) {
        const s16x8 kf = *(const s16x8*)(Kc + loff[ks][c]);
        a0 = __builtin_amdgcn_mfma_f32_16x16x32_bf16(kf, qf0[c], a0, 0, 0, 0);
        a1 = __builtin_amdgcn_mfma_f32_16x16x32_bf16(kf, qf1[c], a1, 0, 0, 0);
      }
      sf0[ks] = a0; sf1[ks] = a1;
    }
    __builtin_amdgcn_s_setprio(0);
    // --- mask (skipped for all-positive tiles); masked scores -> -10000 -> exp2 -> 0 ---
    if ((bm0 >> kt) & 1ull) {
      const int qg_ = qb * 128 + w * 16 + ln;
#pragma unroll
      for (int ks = 0; ks < 4; ++ks) {
        const int4 mv = *(const int4*)(mask + ((size_t)b * Tt + qg_) * Tt + kt * 64 + ks * 16 + g * 4);
        if (mv.x <= 0) sf0[ks][0] = -10000.f;
        if (mv.y <= 0) sf0[ks][1] = -10000.f;
        if (mv.z <= 0) sf0[ks][2] = -10000.f;
        if (mv.w <= 0) sf0[ks][3] = -10000.f;
      }
    }
    if ((bm1 >> kt) & 1ull) {
      const int qg_ = qb * 128 + 64 + w * 16 + ln;
#pragma unroll
      for (int ks = 0; ks < 4; ++ks) {
        const int4 mv = *(const int4*)(mask + ((size_t)b * Tt + qg_) * Tt + kt * 64 + ks * 16 + g * 4);
        if (mv.x <= 0) sf1[ks][0] = -10000.f;
        if (mv.y <= 0) sf1[ks][1] = -10000.f;
        if (mv.z <= 0) sf1[ks][2] = -10000.f;
        if (mv.w <= 0) sf1[ks][3] = -10000.f;
      }
    }
    // --- raw exp2 (no max subtraction) ---
#pragma unroll
    for (int ks = 0; ks < 4; ++ks) {
#pragma unroll
      for (int r = 0; r < 4; ++r) {
        sf0[ks][r] = __builtin_amdgcn_exp2f(sf0[ks][r]);
        sf1[ks][r] = __builtin_amdgcn_exp2f(sf1[ks][r]);
      }
    }
    // --- pack P A-frags via v_cvt_pk: word w of pa{j}[c] = slots (2w,2w+1), i=4f+r ---
    i32x4 paw0[2], paw1[2];
#pragma unroll
    for (int c = 0; c < 2; c++)
#pragma unroll
      for (int f = 0; f < 2; f++)
#pragma unroll
        for (int hh = 0; hh < 2; hh++) {
          paw0[c][f * 2 + hh] = cvt_pk_bf16(sf0[2 * c + f][2 * hh], sf0[2 * c + f][2 * hh + 1]);
          paw1[c][f * 2 + hh] = cvt_pk_bf16(sf1[2 * c + f][2 * hh], sf1[2 * c + f][2 * hh + 1]);
        }
    const s16x8 pa00 = __builtin_bit_cast(s16x8, paw0[0]);
    const s16x8 pa01 = __builtin_bit_cast(s16x8, paw0[1]);
    const s16x8 pa10 = __builtin_bit_cast(s16x8, paw1[0]);
    const s16x8 pa11 = __builtin_bit_cast(s16x8, paw1[1]);
    // --- PV + l on MFMA pipe: l partial = mfma(pa, ones) (every out col = row sum) ---
    __builtin_amdgcn_s_setprio(1);
    accl0 = __builtin_amdgcn_mfma_f32_16x16x32_bf16(pa00, onesf, accl0, 0, 0, 0);
    accl0 = __builtin_amdgcn_mfma_f32_16x16x32_bf16(pa01, onesf, accl0, 0, 0, 0);
    accl1 = __builtin_amdgcn_mfma_f32_16x16x32_bf16(pa10, onesf, accl1, 0, 0, 0);
    accl1 = __builtin_amdgcn_mfma_f32_16x16x32_bf16(pa11, onesf, accl1, 0, 0, 0);
#pragma unroll
    for (int ds = 0; ds < 4; ++ds) {
#pragma unroll
      for (int c = 0; c < 2; ++c) {
        const s16x8 vf = *(const s16x8*)(Vc + loff[ds][c]);
        o0[ds] = __builtin_amdgcn_mfma_f32_16x16x32_bf16(c == 0 ? pa00 : pa01, vf, o0[ds], 0, 0, 0);
        o1[ds] = __builtin_amdgcn_mfma_f32_16x16x32_bf16(c == 0 ? pa10 : pa11, vf, o1[ds], 0, 0, 0);
      }
    }
    __builtin_amdgcn_s_setprio(0);
  };

  // main loop: 16 barriers; each stage issued right after a barrier, drained by the NEXT one
  for (int kt = 0; kt < 32; kt += 4) {
    body(0, kt);
    body(1, kt + 1);
    __syncthreads();
    if (kt + 4 < 32) stage2(Ks[0], Vs[0], Ks[1], Vs[1]);
    body(2, kt + 2);
    body(3, kt + 3);
    __syncthreads();
    if (kt + 6 < 32) stage2(Ks[2], Vs[2], Ks[3], Vs[3]);
  }

  // --- epilogue: l already per-row in accl (no shuffles), normalize, store bf16 ---
  float inv0[4], inv1[4];
#pragma unroll
  for (int r = 0; r < 4; ++r) {
    inv0[r] = 1.0f / accl0[r];
    inv1[r] = 1.0f / accl1[r];
  }
  ushort* AOg0 = AO + ((size_t)b * Tt + qb * 128 + w * 16) * Ff + h * Dk;
  ushort* AOg1 = AOg0 + (size_t)64 * Ff;
#pragma unroll
  for (int ds = 0; ds < 4; ++ds)
#pragma unroll
    for (int r = 0; r < 4; ++r) {
      AOg0[(size_t)(g * 4 + r) * Ff + ds * 16 + ln] = f2bf(o0[ds][r] * inv0[r]);
      AOg1[(size_t)(g * 4 + r) * Ff + ds * 16 + ln] = f2bf(o1[ds][r] * inv1[r]);
    }
}

// ---------------- host launch ----------------
extern "C" void kernel_launch(void* const* d_in, const int* in_sizes, int n_in,
                              void* d_out, int out_size, void* d_ws, size_t ws_size,
                              hipStream_t stream) {
  const float* query = (const float*)d_in[0];
  const float* key_  = (const float*)d_in[1];
  const float* value = (const float*)d_in[2];
  const int*   mask  = (const int*)d_in[3];
  const float* Wq = (const float*)d_in[4];  const float* bq = (const float*)d_in[5];
  const float* Wk = (const float*)d_in[6];  const float* bk = (const float*)d_in[7];
  const float* Wv = (const float*)d_in[8];  const float* bv = (const float*)d_in[9];
  const float* Wo = (const float*)d_in[10]; const float* bo = (const float*)d_in[11];
  float* Out = (float*)d_out;

  constexpr size_t SZ_X = (size_t)Mm * Ff * 2;  // 8 MB bf16 matrix
  constexpr size_t SZ_W = (size_t)Ff * Ff * 2;  // 2 MB bf16 weight
  uintptr_t p = (uintptr_t)d_ws;
  auto alloc = [&](size_t sz) { void* r = (void*)p; p += (sz + 255) & ~(size_t)255; return r; };
  ushort* AO  = (ushort*)alloc(SZ_X);  // flash output
  ushort* Wqt = (ushort*)alloc(SZ_W);
  ushort* Wkt = (ushort*)alloc(SZ_W);
  ushort* Wvt = (ushort*)alloc(SZ_W);
  ushort* Wot = (ushort*)alloc(SZ_W);
  ushort* Qp  = (ushort*)alloc(SZ_X);
  ushort* Kp  = (ushort*)alloc(SZ_X);
  ushort* Vpt = (ushort*)alloc(SZ_X);  // [b][d][kv], pi-ordered columns, written by qkv_gemm z=2
  int* flags = (int*)alloc((size_t)Bb * 32 * 32 * 4);

  prep_kernel<<<dim3(3072), 256, 0, stream>>>(Wq, Wk, Wv, Wo, Wqt, Wkt, Wvt, Wot, mask, flags);
  qkv_gemm_kernel<<<dim3(8, 32, 3), 256, 0, stream>>>(query, key_, value, Wqt, Wkt, Wvt,
                                                      bq, bk, bv, Qp, Kp, Vpt);
  flash_kernel<<<dim3(16, 16, 2), 256, 0, stream>>>(Qp, Kp, Vpt, flags, mask, AO);
  out_gemm_kernel<<<dim3(8, 32), 256, 0, stream>>>(AO, Wot, bo, Out);
}

// Round 15
// 123.768 us; speedup vs baseline: 1.0611x; 1.0611x over previous
//
#include <hip/hip_runtime.h>
#include <hip/hip_bf16.h>
#include <stdint.h>

typedef float  f32x4 __attribute__((ext_vector_type(4)));
typedef short  s16x8 __attribute__((ext_vector_type(8)));
typedef short  s16x4 __attribute__((ext_vector_type(4)));
typedef int    i32x4 __attribute__((ext_vector_type(4)));

#define DI __device__ __forceinline__

constexpr int Bb = 2, Tt = 2048, Ff = 1024, Hh = 16, Dk = 64;
constexpr int Mm = Bb * Tt;  // 4096 rows
constexpr float LOG2E = 1.44269504088896340736f;

DI ushort f2bf(float f) {  // round-to-nearest-even f32 -> bf16 (raw bits)
  unsigned u = __float_as_uint(f);
  unsigned r = (u + 0x7fffu + ((u >> 16) & 1u)) >> 16;
  return (ushort)r;
}

DI int cvt_pk_bf16(float lo, float hi) {  // packed f32x2 -> bf16x2 (v_cvt_pk_bf16_f32)
  __hip_bfloat162 t = __float22bfloat162_rn(make_float2(lo, hi));
  int w;
  __builtin_memcpy(&w, &t, 4);
  return w;
}

DI s16x8 pack8(const float4& a, const float4& b) {  // 8 f32 -> 8 bf16 (RNE, == old cvt3 rounding)
  i32x4 w;
  w[0] = cvt_pk_bf16(a.x, a.y); w[1] = cvt_pk_bf16(a.z, a.w);
  w[2] = cvt_pk_bf16(b.x, b.y); w[3] = cvt_pk_bf16(b.z, b.w);
  return __builtin_bit_cast(s16x8, w);
}

DI void gload16(const void* g, void* l) {  // async global->LDS, 16B/lane, dst = wave-uniform base + lane*16
  __builtin_amdgcn_global_load_lds(
      (__attribute__((address_space(1))) void*)g,
      (__attribute__((address_space(3))) void*)l, 16, 0, 0);
}

DI void wait_vm4() { asm volatile("s_waitcnt vmcnt(4)" ::: "memory"); }
DI void wait_vm6() { asm volatile("s_waitcnt vmcnt(6)" ::: "memory"); }
DI void wait_vm0() { asm volatile("s_waitcnt vmcnt(0)" ::: "memory"); }
DI void wait_lgkm0() { asm volatile("s_waitcnt lgkmcnt(0)" ::: "memory"); }

// ---------------- merged prep: wtrans (1024 blk) + maskflag (2048 blk) ----------------
__global__ __launch_bounds__(256) void prep_kernel(
    const float* __restrict__ W0, const float* __restrict__ W1,
    const float* __restrict__ W2, const float* __restrict__ W3,
    ushort* __restrict__ Wt0, ushort* __restrict__ Wt1,
    ushort* __restrict__ Wt2, ushort* __restrict__ Wt3,
    const int* __restrict__ mask, int* __restrict__ flags) {
  const int bid = blockIdx.x;
  const int t = threadIdx.x;
  if (bid < 1024) {
    // --- wtrans: W[k][n] f32 -> Wt[n][k] bf16 ---
    const int z = bid >> 8, bx = bid & 15, by = (bid >> 4) & 15;
    const float* W; ushort* Wt;
    switch (z) {
      case 0: W = W0; Wt = Wt0; break;
      case 1: W = W1; Wt = Wt1; break;
      case 2: W = W2; Wt = Wt2; break;
      default: W = W3; Wt = Wt3; break;
    }
    __shared__ float tile[64][65];
    const int k0 = by * 64, n0 = bx * 64;
    const int r = t >> 4, c4 = (t & 15) * 4;
#pragma unroll
    for (int i = 0; i < 4; i++) {
      const int row = r + i * 16;
      const float4 v = *(const float4*)(W + (size_t)(k0 + row) * Ff + n0 + c4);
      tile[row][c4] = v.x; tile[row][c4 + 1] = v.y; tile[row][c4 + 2] = v.z; tile[row][c4 + 3] = v.w;
    }
    __syncthreads();
#pragma unroll
    for (int i = 0; i < 4; i++) {
      const int n = r + i * 16;
      s16x4 o;
#pragma unroll
      for (int j = 0; j < 4; j++) o[j] = (short)f2bf(tile[c4 + j][n]);
      *(s16x4*)(Wt + (size_t)(n0 + n) * Ff + k0 + c4) = o;
    }
  } else {
    // --- maskflag: flag=1 iff whole 64x64 tile > 0 ---
    const int mb = bid - 1024;
    const int kb = mb & 31, qb = (mb >> 5) & 31, bz = mb >> 10;
    __shared__ int s;
    if (t == 0) s = 1;
    __syncthreads();
    int ok = 1;
#pragma unroll
    for (int i = 0; i < 4; i++) {
      const int row = qb * 64 + (t >> 4) + i * 16;
      const int4 v = *(const int4*)(mask + ((size_t)bz * Tt + row) * Tt + kb * 64 + (t & 15) * 4);
      ok &= (v.x > 0) & (v.y > 0) & (v.z > 0) & (v.w > 0);
    }
    atomicAnd(&s, ok);
    __syncthreads();
    if (t == 0) flags[(bz * 32 + qb) * 32 + kb] = s;
  }
}

// ---------------- bf16 GEMM (bf16 A via gload), BK=32 ring-3, chunk-XOR swizzled ----------------
// Chunk c of row r stored at slot s = c^((r>>1)&3): per 16-lane phase the b128 reads tile
// banks 0-15 / 16-31 at 2 lanes/quad = 2-way (free). 0 conflicts measured (round 12).
DI void gemm_core(const ushort* __restrict__ A, const ushort* __restrict__ Bt,
                  const float* __restrict__ bias, float* __restrict__ Cout, int m0, int n0) {
  __shared__ ushort Ads[3][128 * 32];  // 24 KB ring
  __shared__ ushort Bds[3][128 * 32];  // 24 KB ring
  const int tid = threadIdx.x, lane = tid & 63, w = tid >> 6;
  const int wr = w >> 1, wc = w & 1;
  const int g = lane >> 4, ln = lane & 15;
  const int strow = tid >> 2;        // staging row 0..63 (also row+64)
  const int sc = tid & 3;            // linear 16B slot within row
  const int sx = (strow >> 1) & 3;   // row swizzle key (same for strow and strow+64)
  const int swch = ((sc ^ sx) * 8);  // pre-swizzled SOURCE chunk offset (ushorts)

  const ushort* Asrc0 = A + (size_t)(m0 + strow) * Ff + swch;
  const ushort* Asrc1 = A + (size_t)(m0 + 64 + strow) * Ff + swch;
  const ushort* Bsrc0 = Bt + (size_t)(n0 + strow) * Ff + swch;
  const ushort* Bsrc1 = Bt + (size_t)(n0 + 64 + strow) * Ff + swch;
  const int dst0 = strow * 32 + sc * 8;          // linear dst = base + lane*16B
  const int dst1 = (64 + strow) * 32 + sc * 8;

  f32x4 acc[4][4];
#pragma unroll
  for (int m = 0; m < 4; m++)
#pragma unroll
    for (int n = 0; n < 4; n++) acc[m][n] = (f32x4){0.f, 0.f, 0.f, 0.f};

  auto stage = [&](int t, int slot) {
    const int k0 = t * 32;
    gload16(Asrc0 + k0, Ads[slot] + dst0);
    gload16(Asrc1 + k0, Ads[slot] + dst1);
    gload16(Bsrc0 + k0, Bds[slot] + dst0);
    gload16(Bsrc1 + k0, Bds[slot] + dst1);
  };

  stage(0, 0);
  stage(1, 1);

  int rs = 0, ws = 2;
  for (int t = 0; t < 32; ++t) {
    if (t < 31) wait_vm4(); else wait_vm0();
    __builtin_amdgcn_s_barrier();
    __builtin_amdgcn_sched_barrier(0);
    if (t < 30) stage(t + 2, ws);
    const ushort* As = Ads[rs];
    const ushort* Bs = Bds[rs];
    s16x8 af[4], bf[4];
#pragma unroll
    for (int m = 0; m < 4; m++) {
      const int ra = wr * 64 + m * 16 + ln;
      af[m] = *(const s16x8*)(As + ra * 32 + ((g ^ ((ra >> 1) & 3)) * 8));
    }
#pragma unroll
    for (int n = 0; n < 4; n++) {
      const int rb = wc * 64 + n * 16 + ln;
      bf[n] = *(const s16x8*)(Bs + rb * 32 + ((g ^ ((rb >> 1) & 3)) * 8));
    }
    __builtin_amdgcn_s_setprio(1);
#pragma unroll
    for (int m = 0; m < 4; m++)
#pragma unroll
      for (int n = 0; n < 4; n++)
        acc[m][n] = __builtin_amdgcn_mfma_f32_16x16x32_bf16(af[m], bf[n], acc[m][n], 0, 0, 0);
    __builtin_amdgcn_s_setprio(0);
    rs = rs == 2 ? 0 : rs + 1;
    ws = ws == 2 ? 0 : ws + 1;
  }
#pragma unroll
  for (int m = 0; m < 4; m++) {
    const int r0 = m0 + wr * 64 + m * 16 + g * 4;
#pragma unroll
    for (int n = 0; n < 4; n++) {
      const int col = n0 + wc * 64 + n * 16 + ln;
      const float bv = bias[col];
#pragma unroll
      for (int r = 0; r < 4; r++)
        Cout[(size_t)(r0 + r) * Ff + col] = acc[m][n][r] + bv;
    }
  }
}

// ---------------- bf16 GEMM with F32 A (fused convert), BK=32 ring-3, swizzled ----------------
// Round-15 = round-12 verbatim (proven best). A reg-staged (T14 issue-early/write-late,
// coalesced 8-f32/thread loads, exactly 6 VM ops/iter -> vmcnt(6)); writeA targets the
// swizzled slot; stageB pre-swizzles the gload source; reads XOR g with (row>>1)&3.
// V-store experiments (rounds 13/14) reverted: traffic fix confirmed but time-negative.
DI void gemm_core_f32a(const float* __restrict__ A, const ushort* __restrict__ Bt,
                       const float* __restrict__ bias, void* __restrict__ Cout, float scale,
                       int mode, int m0, int n0) {
  __shared__ ushort Ads[3][128 * 32];  // 24 KB ring
  __shared__ ushort Bds[3][128 * 32];  // 24 KB ring
  const int tid = threadIdx.x, lane = tid & 63, w = tid >> 6;
  const int wr = w >> 1, wc = w & 1;
  const int g = lane >> 4, ln = lane & 15;
  const int strow = tid >> 2;
  const int sc = tid & 3;
  const int sx = (strow >> 1) & 3;   // same key for strow and strow+64
  const int stcf = sc * 8;           // this thread's OWN chunk (floats) — A loads stay coalesced

  const float*  Asrc0 = A + (size_t)(m0 + strow) * Ff + stcf;
  const float*  Asrc1 = A + (size_t)(m0 + 64 + strow) * Ff + stcf;
  const ushort* Bsrc0 = Bt + (size_t)(n0 + strow) * Ff + ((sc ^ sx) * 8);
  const ushort* Bsrc1 = Bt + (size_t)(n0 + 64 + strow) * Ff + ((sc ^ sx) * 8);
  const int dstA0 = strow * 32 + ((sc ^ sx) * 8);         // SWIZZLED ds_write slot
  const int dstA1 = (64 + strow) * 32 + ((sc ^ sx) * 8);
  const int dstB0 = strow * 32 + sc * 8;                  // linear gload dst (= base + lane*16B)
  const int dstB1 = (64 + strow) * 32 + sc * 8;

  float4 rA0a, rA0b, rA1a, rA1b;  // staged A for next tile (2 rows x 8 f32)
  auto loadA = [&](int t) {
    const float* p0 = Asrc0 + t * 32;
    const float* p1 = Asrc1 + t * 32;
    rA0a = *(const float4*)p0; rA0b = *(const float4*)(p0 + 4);
    rA1a = *(const float4*)p1; rA1b = *(const float4*)(p1 + 4);
  };
  auto writeA = [&](int slot) {
    *(s16x8*)(Ads[slot] + dstA0) = pack8(rA0a, rA0b);
    *(s16x8*)(Ads[slot] + dstA1) = pack8(rA1a, rA1b);
  };
  auto stageB = [&](int t, int slot) {
    const int k0 = t * 32;
    gload16(Bsrc0 + k0, Bds[slot] + dstB0);
    gload16(Bsrc1 + k0, Bds[slot] + dstB1);
  };

  f32x4 acc[4][4];
#pragma unroll
  for (int m = 0; m < 4; m++)
#pragma unroll
    for (int n = 0; n < 4; n++) acc[m][n] = (f32x4){0.f, 0.f, 0.f, 0.f};

  // prologue: A(0) regs -> LDS slot0 (compiler-waited); then A(1) regs; B(0),B(1) gloads.
  loadA(0);
  writeA(0);
  stageB(0, 0);   // older than the 6 newest below -> drained by first wait_vm6
  loadA(1);       // 4 loads
  stageB(1, 1);   // 2 gloads  => newest 6 = A(1)x4 + B(1)x2

  int rs = 0, ps = 1, ws = 2;
  for (int t = 0; t < 32; ++t) {
    if (t < 31) wait_vm6(); else wait_vm0();  // drains B(t) + older; leaves A(t+1),B(t+1)
    wait_lgkm0();                             // publish last iter's A ds_writes
    __builtin_amdgcn_s_barrier();
    __builtin_amdgcn_sched_barrier(0);
    if (t < 31) writeA(ps);                   // A(t+1) regs -> slot (t+1)%3 (auto-waited)
    if (t < 30) { loadA(t + 2); stageB(t + 2, ws); }  // exactly 6 VM ops
    const ushort* As = Ads[rs];
    const ushort* Bs = Bds[rs];
    s16x8 af[4], bf[4];
#pragma unroll
    for (int m = 0; m < 4; m++) {
      const int ra = wr * 64 + m * 16 + ln;
      af[m] = *(const s16x8*)(As + ra * 32 + ((g ^ ((ra >> 1) & 3)) * 8));
    }
#pragma unroll
    for (int n = 0; n < 4; n++) {
      const int rb = wc * 64 + n * 16 + ln;
      bf[n] = *(const s16x8*)(Bs + rb * 32 + ((g ^ ((rb >> 1) & 3)) * 8));
    }
    __builtin_amdgcn_s_setprio(1);
#pragma unroll
    for (int m = 0; m < 4; m++)
#pragma unroll
      for (int n = 0; n < 4; n++)
        acc[m][n] = __builtin_amdgcn_mfma_f32_16x16x32_bf16(af[m], bf[n], acc[m][n], 0, 0, 0);
    __builtin_amdgcn_s_setprio(0);
    rs = rs == 2 ? 0 : rs + 1;
    ps = ps == 2 ? 0 : ps + 1;
    ws = ws == 2 ? 0 : ws + 1;
  }
#pragma unroll
  for (int m = 0; m < 4; m++) {
    const int r0 = m0 + wr * 64 + m * 16 + g * 4;
#pragma unroll
    for (int n = 0; n < 4; n++) {
      const int col = n0 + wc * 64 + n * 16 + ln;
      const float bv = bias[col];
      if (mode == 2) {
        // V-fragment store: batch bb, row-in-batch rb, pi^-1 on kv within 64-block
        const int bb = r0 >> 11, rb = r0 & 2047;
        const int x = rb & 63;
        const int pbase = (x & 0x20) | ((x & 0x0C) << 1) | ((x & 0x10) >> 2);
        s16x4 o4;
#pragma unroll
        for (int r = 0; r < 4; r++) o4[r] = (short)f2bf(acc[m][n][r] + bv);
        *(s16x4*)((ushort*)Cout + ((size_t)bb * Ff + col) * Tt + (rb & ~63) + pbase) = o4;
      } else {
#pragma unroll
        for (int r = 0; r < 4; r++)
          ((ushort*)Cout)[(size_t)(r0 + r) * Ff + col] = f2bf((acc[m][n][r] + bv) * scale);
      }
    }
  }
}

__global__ __launch_bounds__(256) void qkv_gemm_kernel(
    const float* __restrict__ Xq, const float* __restrict__ Xk, const float* __restrict__ Xv,
    const ushort* __restrict__ Wqt, const ushort* __restrict__ Wkt, const ushort* __restrict__ Wvt,
    const float* __restrict__ bq, const float* __restrict__ bk, const float* __restrict__ bv,
    ushort* __restrict__ Qb, ushort* __restrict__ Kb, ushort* __restrict__ Vpt) {
  // T1: XCD-chunked bijective block swizzle (768 blocks -> 96 contiguous per XCD)
  const int lin = blockIdx.x + 8 * blockIdx.y + 256 * blockIdx.z;
  const int work = (lin & 7) * 96 + (lin >> 3);
  const int z = work >> 8;
  const int r = work & 255;
  const int m0 = (r >> 3) * 128, n0 = (r & 7) * 128;
  const float* A = z == 0 ? Xq : (z == 1 ? Xk : Xv);
  const ushort* Wt = z == 0 ? Wqt : (z == 1 ? Wkt : Wvt);
  const float* bias = z == 0 ? bq : (z == 1 ? bk : bv);
  void* C = z == 0 ? (void*)Qb : (z == 1 ? (void*)Kb : (void*)Vpt);
  const float scale = z == 0 ? 0.125f * LOG2E : 1.0f;  // fold 1/sqrt(64) and log2(e) into Q
  gemm_core_f32a(A, Wt, bias, C, scale, z == 2 ? 2 : 1, m0, n0);
}

__global__ __launch_bounds__(256) void out_gemm_kernel(const ushort* __restrict__ AO,
                                                       const ushort* __restrict__ Wot,
                                                       const float* __restrict__ bo,
                                                       float* __restrict__ Out) {
  // T1: XCD-chunked bijective block swizzle (256 blocks -> 32 contiguous per XCD)
  const int lin = blockIdx.x + 8 * blockIdx.y;
  const int work = (lin & 7) * 32 + (lin >> 3);
  const int m0 = (work >> 3) * 128, n0 = (work & 7) * 128;
  gemm_core(AO, Wot, bo, Out, m0, n0);
}

// ---------------- flash attention (round-8 best: max-free exp2, QBLK=128, ring-4 pair sync) ----------------
// grid (qb=16, h=16, b=2), 256 thr (4 waves). BQ=128 (two 16-row groups/wave), BK=64, D=64.
// Ring-4 (64 KB LDS): per half-iter {compute 2 tiles -> __syncthreads -> stage next pair};
// each staged pair gets a full 2-tile compute phase to land; 16 barriers total.
// l on MFMA pipe via ones-B trick (acc reg r = l for q-row 4g+r).
__global__ __launch_bounds__(256) void flash_kernel(
    const ushort* __restrict__ Qb, const ushort* __restrict__ Kb, const ushort* __restrict__ Vpt,
    const int* __restrict__ flags, const int* __restrict__ mask, ushort* __restrict__ AO) {
  __shared__ ushort Ks[4][64 * 64];
  __shared__ ushort Vs[4][64 * 64];
  // T1: XCD-chunked bijective block swizzle (512 blocks -> 64 per XCD = 4 heads' KV, L2-fit)
  const int lin = blockIdx.x + 16 * (blockIdx.y + 16 * blockIdx.z);
  const int work = (lin & 7) * 64 + (lin >> 3);
  const int qb = work & 15, h = (work >> 4) & 15, b = work >> 8;
  const int tid = threadIdx.x, lane = tid & 63, w = tid >> 6;
  const int g = lane >> 4, ln = lane & 15;

  const ushort* Qg = Qb + ((size_t)b * Tt + qb * 128) * Ff + h * Dk;
  const ushort* Kg = Kb + ((size_t)b * Tt) * Ff + h * Dk;
  const ushort* Vg = Vpt + (size_t)(b * Ff + h * Dk) * Tt;  // rows d, stride Tt, cols pi-ordered

  const int srow = lane >> 3;
  const int swzch = ((lane & 7) ^ srow) * 8;  // inverse-swizzled source chunk (128B rows need XOR)

  // persistent staging source pointers (advance one PAIR of KV tiles per stage2)
  const ushort* ksrc0 = Kg + (size_t)(w * 16 + srow) * Ff + swzch;
  const ushort* ksrc1 = ksrc0 + (size_t)8 * Ff;
  const ushort* vsrc0 = Vg + (size_t)(w * 16 + srow) * Tt + swzch;
  const ushort* vsrc1 = vsrc0 + (size_t)8 * Tt;

  // Q fragments DIRECT from global (one-time read): qf{j}[c] = Q[j*64 + w*16+ln][c*32+g*8 ..+7]
  s16x8 qf0[2], qf1[2];
  {
    const ushort* Qrow0 = Qg + (size_t)(w * 16 + ln) * Ff;
    const ushort* Qrow1 = Qrow0 + (size_t)64 * Ff;
    qf0[0] = *(const s16x8*)(Qrow0 + g * 8);
    qf0[1] = *(const s16x8*)(Qrow0 + 32 + g * 8);
    qf1[0] = *(const s16x8*)(Qrow1 + g * 8);
    qf1[1] = *(const s16x8*)(Qrow1 + 32 + g * 8);
  }
  const int* flagrow0 = flags + (b * 32 + qb * 2) * 32;
  const int f0 = (lane < 32) ? flagrow0[lane] : 1;
  const int f1 = (lane < 32) ? flagrow0[32 + lane] : 1;

  // stage a PAIR of consecutive KV tiles into two slots, advance pointers by 2 tiles
  auto stage2 = [&](ushort* Kd0, ushort* Vd0, ushort* Kd1, ushort* Vd1) {
    const int r0 = w * 16;
    gload16(ksrc0, Kd0 + r0 * 64);
    gload16(ksrc1, Kd0 + (r0 + 8) * 64);
    gload16(vsrc0, Vd0 + r0 * 64);
    gload16(vsrc1, Vd0 + (r0 + 8) * 64);
    gload16(ksrc0 + (size_t)64 * Ff, Kd1 + r0 * 64);
    gload16(ksrc1 + (size_t)64 * Ff, Kd1 + (r0 + 8) * 64);
    gload16(vsrc0 + 64, Vd1 + r0 * 64);
    gload16(vsrc1 + 64, Vd1 + (r0 + 8) * 64);
    ksrc0 += (size_t)128 * Ff; ksrc1 += (size_t)128 * Ff;
    vsrc0 += 128; vsrc1 += 128;
  };

  // prologue: stage tiles 0..3 into slots 0..3, full drain once
  stage2(Ks[0], Vs[0], Ks[1], Vs[1]);
  stage2(Ks[2], Vs[2], Ks[3], Vs[3]);
  __syncthreads();
  const unsigned long long bm0 = __ballot(f0 == 0);
  const unsigned long long bm1 = __ballot(f1 == 0);

  // hoisted LDS read byte-offsets: rows i*16+ln, chunk c — shared by QK (K) and PV (V) reads
  int loff[4][2];
#pragma unroll
  for (int i = 0; i < 4; i++)
#pragma unroll
    for (int c = 0; c < 2; c++) {
      const int row = i * 16 + ln;
      loff[i][c] = row * 128 + ((c * 64 + g * 16) ^ ((row & 7) << 4));
    }
  const char* Kbase = (const char*)&Ks[0][0];
  const char* Vbase = (const char*)&Vs[0][0];

  s16x8 onesf;
#pragma unroll
  for (int j = 0; j < 8; ++j) onesf[j] = (short)0x3F80;  // bf16 1.0

  f32x4 accl0 = (f32x4){0.f, 0.f, 0.f, 0.f}, accl1 = (f32x4){0.f, 0.f, 0.f, 0.f};
  f32x4 o0[4], o1[4];
#pragma unroll
  for (int ds = 0; ds < 4; ds++) { o0[ds] = (f32x4){0.f, 0.f, 0.f, 0.f}; o1[ds] = (f32x4){0.f, 0.f, 0.f, 0.f}; }

  auto body = [&](int slot, int kt) {
    const char* Kc = Kbase + slot * 8192;
    const char* Vc = Vbase + slot * 8192;
    // --- S'^T = K * Q^T (log2 domain); each kf feeds BOTH q-groups ---
    f32x4 sf0[4], sf1[4];
    __builtin_amdgcn_s_setprio(1);
#pragma unroll
    for (int ks = 0; ks < 4; ++ks) {
      f32x4 a0 = (f32x4){0.f, 0.f, 0.f, 0.f};
      f32x4 a1 = (f32x4){0.f, 0.f, 0.f, 0.f};
#pragma unroll
      for (int c = 0; c < 2; c++) {
        const s16x8 kf = *(const s16x8*)(Kc + loff[ks][c]);
        a0 = __builtin_amdgcn_mfma_f32_16x16x32_bf16(kf, qf0[c], a0, 0, 0, 0);
        a1 = __builtin_amdgcn_mfma_f32_16x16x32_bf16(kf, qf1[c], a1, 0, 0, 0);
      }
      sf0[ks] = a0; sf1[ks] = a1;
    }
    __builtin_amdgcn_s_setprio(0);
    // --- mask (skipped for all-positive tiles); masked scores -> -10000 -> exp2 -> 0 ---
    if ((bm0 >> kt) & 1ull) {
      const int qg_ = qb * 128 + w * 16 + ln;
#pragma unroll
      for (int ks = 0; ks < 4; ++ks) {
        const int4 mv = *(const int4*)(mask + ((size_t)b * Tt + qg_) * Tt + kt * 64 + ks * 16 + g * 4);
        if (mv.x <= 0) sf0[ks][0] = -10000.f;
        if (mv.y <= 0) sf0[ks][1] = -10000.f;
        if (mv.z <= 0) sf0[ks][2] = -10000.f;
        if (mv.w <= 0) sf0[ks][3] = -10000.f;
      }
    }
    if ((bm1 >> kt) & 1ull) {
      const int qg_ = qb * 128 + 64 + w * 16 + ln;
#pragma unroll
      for (int ks = 0; ks < 4; ++ks) {
        const int4 mv = *(const int4*)(mask + ((size_t)b * Tt + qg_) * Tt + kt * 64 + ks * 16 + g * 4);
        if (mv.x <= 0) sf1[ks][0] = -10000.f;
        if (mv.y <= 0) sf1[ks][1] = -10000.f;
        if (mv.z <= 0) sf1[ks][2] = -10000.f;
        if (mv.w <= 0) sf1[ks][3] = -10000.f;
      }
    }
    // --- raw exp2 (no max subtraction) ---
#pragma unroll
    for (int ks = 0; ks < 4; ++ks) {
#pragma unroll
      for (int r = 0; r < 4; ++r) {
        sf0[ks][r] = __builtin_amdgcn_exp2f(sf0[ks][r]);
        sf1[ks][r] = __builtin_amdgcn_exp2f(sf1[ks][r]);
      }
    }
    // --- pack P A-frags via v_cvt_pk: word w of pa{j}[c] = slots (2w,2w+1), i=4f+r ---
    i32x4 paw0[2], paw1[2];
#pragma unroll
    for (int c = 0; c < 2; c++)
#pragma unroll
      for (int f = 0; f < 2; f++)
#pragma unroll
        for (int hh = 0; hh < 2; hh++) {
          paw0[c][f * 2 + hh] = cvt_pk_bf16(sf0[2 * c + f][2 * hh], sf0[2 * c + f][2 * hh + 1]);
          paw1[c][f * 2 + hh] = cvt_pk_bf16(sf1[2 * c + f][2 * hh], sf1[2 * c + f][2 * hh + 1]);
        }
    const s16x8 pa00 = __builtin_bit_cast(s16x8, paw0[0]);
    const s16x8 pa01 = __builtin_bit_cast(s16x8, paw0[1]);
    const s16x8 pa10 = __builtin_bit_cast(s16x8, paw1[0]);
    const s16x8 pa11 = __builtin_bit_cast(s16x8, paw1[1]);
    // --- PV + l on MFMA pipe: l partial = mfma(pa, ones) (every out col = row sum) ---
    __builtin_amdgcn_s_setprio(1);
    accl0 = __builtin_amdgcn_mfma_f32_16x16x32_bf16(pa00, onesf, accl0, 0, 0, 0);
    accl0 = __builtin_amdgcn_mfma_f32_16x16x32_bf16(pa01, onesf, accl0, 0, 0, 0);
    accl1 = __builtin_amdgcn_mfma_f32_16x16x32_bf16(pa10, onesf, accl1, 0, 0, 0);
    accl1 = __builtin_amdgcn_mfma_f32_16x16x32_bf16(pa11, onesf, accl1, 0, 0, 0);
#pragma unroll
    for (int ds = 0; ds < 4; ++ds) {
#pragma unroll
      for (int c = 0; c < 2; ++c) {
        const s16x8 vf = *(const s16x8*)(Vc + loff[ds][c]);
        o0[ds] = __builtin_amdgcn_mfma_f32_16x16x32_bf16(c == 0 ? pa00 : pa01, vf, o0[ds], 0, 0, 0);
        o1[ds] = __builtin_amdgcn_mfma_f32_16x16x32_bf16(c == 0 ? pa10 : pa11, vf, o1[ds], 0, 0, 0);
      }
    }
    __builtin_amdgcn_s_setprio(0);
  };

  // main loop: 16 barriers; each stage issued right after a barrier, drained by the NEXT one
  for (int kt = 0; kt < 32; kt += 4) {
    body(0, kt);
    body(1, kt + 1);
    __syncthreads();
    if (kt + 4 < 32) stage2(Ks[0], Vs[0], Ks[1], Vs[1]);
    body(2, kt + 2);
    body(3, kt + 3);
    __syncthreads();
    if (kt + 6 < 32) stage2(Ks[2], Vs[2], Ks[3], Vs[3]);
  }

  // --- epilogue: l already per-row in accl (no shuffles), normalize, store bf16 ---
  float inv0[4], inv1[4];
#pragma unroll
  for (int r = 0; r < 4; ++r) {
    inv0[r] = 1.0f / accl0[r];
    inv1[r] = 1.0f / accl1[r];
  }
  ushort* AOg0 = AO + ((size_t)b * Tt + qb * 128 + w * 16) * Ff + h * Dk;
  ushort* AOg1 = AOg0 + (size_t)64 * Ff;
#pragma unroll
  for (int ds = 0; ds < 4; ++ds)
#pragma unroll
    for (int r = 0; r < 4; ++r) {
      AOg0[(size_t)(g * 4 + r) * Ff + ds * 16 + ln] = f2bf(o0[ds][r] * inv0[r]);
      AOg1[(size_t)(g * 4 + r) * Ff + ds * 16 + ln] = f2bf(o1[ds][r] * inv1[r]);
    }
}

// ---------------- host launch ----------------
extern "C" void kernel_launch(void* const* d_in, const int* in_sizes, int n_in,
                              void* d_out, int out_size, void* d_ws, size_t ws_size,
                              hipStream_t stream) {
  const float* query = (const float*)d_in[0];
  const float* key_  = (const float*)d_in[1];
  const float* value = (const float*)d_in[2];
  const int*   mask  = (const int*)d_in[3];
  const float* Wq = (const float*)d_in[4];  const float* bq = (const float*)d_in[5];
  const float* Wk = (const float*)d_in[6];  const float* bk = (const float*)d_in[7];
  const float* Wv = (const float*)d_in[8];  const float* bv = (const float*)d_in[9];
  const float* Wo = (const float*)d_in[10]; const float* bo = (const float*)d_in[11];
  float* Out = (float*)d_out;

  constexpr size_t SZ_X = (size_t)Mm * Ff * 2;  // 8 MB bf16 matrix
  constexpr size_t SZ_W = (size_t)Ff * Ff * 2;  // 2 MB bf16 weight
  uintptr_t p = (uintptr_t)d_ws;
  auto alloc = [&](size_t sz) { void* r = (void*)p; p += (sz + 255) & ~(size_t)255; return r; };
  ushort* AO  = (ushort*)alloc(SZ_X);  // flash output
  ushort* Wqt = (ushort*)alloc(SZ_W);
  ushort* Wkt = (ushort*)alloc(SZ_W);
  ushort* Wvt = (ushort*)alloc(SZ_W);
  ushort* Wot = (ushort*)alloc(SZ_W);
  ushort* Qp  = (ushort*)alloc(SZ_X);
  ushort* Kp  = (ushort*)alloc(SZ_X);
  ushort* Vpt = (ushort*)alloc(SZ_X);  // [b][d][kv], pi-ordered columns, written by qkv_gemm z=2
  int* flags = (int*)alloc((size_t)Bb * 32 * 32 * 4);

  prep_kernel<<<dim3(3072), 256, 0, stream>>>(Wq, Wk, Wv, Wo, Wqt, Wkt, Wvt, Wot, mask, flags);
  qkv_gemm_kernel<<<dim3(8, 32, 3), 256, 0, stream>>>(query, key_, value, Wqt, Wkt, Wvt,
                                                      bq, bk, bv, Qp, Kp, Vpt);
  flash_kernel<<<dim3(16, 16, 2), 256, 0, stream>>>(Qp, Kp, Vpt, flags, mask, AO);
  out_gemm_kernel<<<dim3(8, 32), 256, 0, stream>>>(AO, Wot, bo, Out);
}

// Round 16
// 120.368 us; speedup vs baseline: 1.0911x; 1.0283x over previous
//
#include <hip/hip_runtime.h>
#include <hip/hip_bf16.h>
#include <stdint.h>

typedef float  f32x4 __attribute__((ext_vector_type(4)));
typedef short  s16x8 __attribute__((ext_vector_type(8)));
typedef short  s16x4 __attribute__((ext_vector_type(4)));
typedef int    i32x4 __attribute__((ext_vector_type(4)));

#define DI __device__ __forceinline__

constexpr int Bb = 2, Tt = 2048, Ff = 1024, Hh = 16, Dk = 64;
constexpr int Mm = Bb * Tt;  // 4096 rows
constexpr float LOG2E = 1.44269504088896340736f;

DI ushort f2bf(float f) {  // round-to-nearest-even f32 -> bf16 (raw bits)
  unsigned u = __float_as_uint(f);
  unsigned r = (u + 0x7fffu + ((u >> 16) & 1u)) >> 16;
  return (ushort)r;
}

DI int cvt_pk_bf16(float lo, float hi) {  // packed f32x2 -> bf16x2 (v_cvt_pk_bf16_f32)
  __hip_bfloat162 t = __float22bfloat162_rn(make_float2(lo, hi));
  int w;
  __builtin_memcpy(&w, &t, 4);
  return w;
}

DI s16x8 pack8(const float4& a, const float4& b) {  // 8 f32 -> 8 bf16 (RNE, == old cvt3 rounding)
  i32x4 w;
  w[0] = cvt_pk_bf16(a.x, a.y); w[1] = cvt_pk_bf16(a.z, a.w);
  w[2] = cvt_pk_bf16(b.x, b.y); w[3] = cvt_pk_bf16(b.z, b.w);
  return __builtin_bit_cast(s16x8, w);
}

DI void gload16(const void* g, void* l) {  // async global->LDS, 16B/lane, dst = wave-uniform base + lane*16
  __builtin_amdgcn_global_load_lds(
      (__attribute__((address_space(1))) void*)g,
      (__attribute__((address_space(3))) void*)l, 16, 0, 0);
}

DI void wait_vm3() { asm volatile("s_waitcnt vmcnt(3)" ::: "memory"); }
DI void wait_vm6() { asm volatile("s_waitcnt vmcnt(6)" ::: "memory"); }
DI void wait_vm0() { asm volatile("s_waitcnt vmcnt(0)" ::: "memory"); }
DI void wait_lgkm0() { asm volatile("s_waitcnt lgkmcnt(0)" ::: "memory"); }

// ---------------- merged prep: wtrans (1024 blk) + maskflag (2048 blk) ----------------
__global__ __launch_bounds__(256) void prep_kernel(
    const float* __restrict__ W0, const float* __restrict__ W1,
    const float* __restrict__ W2, const float* __restrict__ W3,
    ushort* __restrict__ Wt0, ushort* __restrict__ Wt1,
    ushort* __restrict__ Wt2, ushort* __restrict__ Wt3,
    const int* __restrict__ mask, int* __restrict__ flags) {
  const int bid = blockIdx.x;
  const int t = threadIdx.x;
  if (bid < 1024) {
    // --- wtrans: W[k][n] f32 -> Wt[n][k] bf16 ---
    const int z = bid >> 8, bx = bid & 15, by = (bid >> 4) & 15;
    const float* W; ushort* Wt;
    switch (z) {
      case 0: W = W0; Wt = Wt0; break;
      case 1: W = W1; Wt = Wt1; break;
      case 2: W = W2; Wt = Wt2; break;
      default: W = W3; Wt = Wt3; break;
    }
    __shared__ float tile[64][65];
    const int k0 = by * 64, n0 = bx * 64;
    const int r = t >> 4, c4 = (t & 15) * 4;
#pragma unroll
    for (int i = 0; i < 4; i++) {
      const int row = r + i * 16;
      const float4 v = *(const float4*)(W + (size_t)(k0 + row) * Ff + n0 + c4);
      tile[row][c4] = v.x; tile[row][c4 + 1] = v.y; tile[row][c4 + 2] = v.z; tile[row][c4 + 3] = v.w;
    }
    __syncthreads();
#pragma unroll
    for (int i = 0; i < 4; i++) {
      const int n = r + i * 16;
      s16x4 o;
#pragma unroll
      for (int j = 0; j < 4; j++) o[j] = (short)f2bf(tile[c4 + j][n]);
      *(s16x4*)(Wt + (size_t)(n0 + n) * Ff + k0 + c4) = o;
    }
  } else {
    // --- maskflag: flag=1 iff whole 64x64 tile > 0 ---
    const int mb = bid - 1024;
    const int kb = mb & 31, qb = (mb >> 5) & 31, bz = mb >> 10;
    __shared__ int s;
    if (t == 0) s = 1;
    __syncthreads();
    int ok = 1;
#pragma unroll
    for (int i = 0; i < 4; i++) {
      const int row = qb * 64 + (t >> 4) + i * 16;
      const int4 v = *(const int4*)(mask + ((size_t)bz * Tt + row) * Tt + kb * 64 + (t & 15) * 4);
      ok &= (v.x > 0) & (v.y > 0) & (v.z > 0) & (v.w > 0);
    }
    atomicAnd(&s, ok);
    __syncthreads();
    if (t == 0) flags[(bz * 32 + qb) * 32 + kb] = s;
  }
}

// ---------------- bf16 GEMM 64x128 tile (out_gemm), BK=32 ring-3, chunk-XOR swizzled ----------------
// Round-16: out_gemm was 1 block/CU (grid 256) -> every vmcnt wait fully exposed. Halved M-tile:
// 64x128 tiles, grid 512 = 2 blocks/CU, LDS 36 KB, acc halved. Same proven BK=32 ring-3 schedule;
// stage = 3 VM ops/iter (1 A + 2 B gloads) -> wait vmcnt(3) keeps tile t+1 in flight.
// Waves 2x2: wave (wr,wc) computes rows wr*32..+31, cols wc*64..+63.
DI void gemm_core64(const ushort* __restrict__ A, const ushort* __restrict__ Bt,
                    const float* __restrict__ bias, float* __restrict__ Cout, int m0, int n0) {
  __shared__ ushort Ads[3][64 * 32];   // 12 KB ring
  __shared__ ushort Bds[3][128 * 32];  // 24 KB ring
  const int tid = threadIdx.x, lane = tid & 63, w = tid >> 6;
  const int wr = w >> 1, wc = w & 1;
  const int g = lane >> 4, ln = lane & 15;
  const int strow = tid >> 2;        // staging row 0..63
  const int sc = tid & 3;            // linear 16B slot within row
  const int sx = (strow >> 1) & 3;   // row swizzle key
  const int swch = ((sc ^ sx) * 8);  // pre-swizzled SOURCE chunk offset (ushorts)

  const ushort* Asrc  = A + (size_t)(m0 + strow) * Ff + swch;          // 64-row A tile
  const ushort* Bsrc0 = Bt + (size_t)(n0 + strow) * Ff + swch;
  const ushort* Bsrc1 = Bt + (size_t)(n0 + 64 + strow) * Ff + swch;
  const int dstA  = strow * 32 + sc * 8;         // linear dst = base + lane*16B
  const int dstB0 = strow * 32 + sc * 8;
  const int dstB1 = (64 + strow) * 32 + sc * 8;

  f32x4 acc[2][4];
#pragma unroll
  for (int m = 0; m < 2; m++)
#pragma unroll
    for (int n = 0; n < 4; n++) acc[m][n] = (f32x4){0.f, 0.f, 0.f, 0.f};

  auto stage = [&](int t, int slot) {
    const int k0 = t * 32;
    gload16(Asrc + k0, Ads[slot] + dstA);
    gload16(Bsrc0 + k0, Bds[slot] + dstB0);
    gload16(Bsrc1 + k0, Bds[slot] + dstB1);
  };

  stage(0, 0);
  stage(1, 1);

  int rs = 0, ws = 2;
  for (int t = 0; t < 32; ++t) {
    if (t < 31) wait_vm3(); else wait_vm0();   // drains tile t's 3; leaves tile t+1's 3
    __builtin_amdgcn_s_barrier();
    __builtin_amdgcn_sched_barrier(0);
    if (t < 30) stage(t + 2, ws);
    const ushort* As = Ads[rs];
    const ushort* Bs = Bds[rs];
    s16x8 af[2], bf[4];
#pragma unroll
    for (int m = 0; m < 2; m++) {
      const int ra = wr * 32 + m * 16 + ln;
      af[m] = *(const s16x8*)(As + ra * 32 + ((g ^ ((ra >> 1) & 3)) * 8));
    }
#pragma unroll
    for (int n = 0; n < 4; n++) {
      const int rb = wc * 64 + n * 16 + ln;
      bf[n] = *(const s16x8*)(Bs + rb * 32 + ((g ^ ((rb >> 1) & 3)) * 8));
    }
    __builtin_amdgcn_s_setprio(1);
#pragma unroll
    for (int m = 0; m < 2; m++)
#pragma unroll
      for (int n = 0; n < 4; n++)
        acc[m][n] = __builtin_amdgcn_mfma_f32_16x16x32_bf16(af[m], bf[n], acc[m][n], 0, 0, 0);
    __builtin_amdgcn_s_setprio(0);
    rs = rs == 2 ? 0 : rs + 1;
    ws = ws == 2 ? 0 : ws + 1;
  }
#pragma unroll
  for (int m = 0; m < 2; m++) {
    const int r0 = m0 + wr * 32 + m * 16 + g * 4;
#pragma unroll
    for (int n = 0; n < 4; n++) {
      const int col = n0 + wc * 64 + n * 16 + ln;
      const float bv = bias[col];
#pragma unroll
      for (int r = 0; r < 4; r++)
        Cout[(size_t)(r0 + r) * Ff + col] = acc[m][n][r] + bv;
    }
  }
}

// ---------------- bf16 GEMM with F32 A (fused convert), BK=32 ring-3, swizzled ----------------
// Round-12-proven best (verbatim). A reg-staged (T14 issue-early/write-late, coalesced
// 8-f32/thread loads, exactly 6 VM ops/iter -> vmcnt(6)); writeA targets the swizzled slot;
// stageB pre-swizzles the gload source; reads XOR g with (row>>1)&3.
DI void gemm_core_f32a(const float* __restrict__ A, const ushort* __restrict__ Bt,
                       const float* __restrict__ bias, void* __restrict__ Cout, float scale,
                       int mode, int m0, int n0) {
  __shared__ ushort Ads[3][128 * 32];  // 24 KB ring
  __shared__ ushort Bds[3][128 * 32];  // 24 KB ring
  const int tid = threadIdx.x, lane = tid & 63, w = tid >> 6;
  const int wr = w >> 1, wc = w & 1;
  const int g = lane >> 4, ln = lane & 15;
  const int strow = tid >> 2;
  const int sc = tid & 3;
  const int sx = (strow >> 1) & 3;   // same key for strow and strow+64
  const int stcf = sc * 8;           // this thread's OWN chunk (floats) — A loads stay coalesced

  const float*  Asrc0 = A + (size_t)(m0 + strow) * Ff + stcf;
  const float*  Asrc1 = A + (size_t)(m0 + 64 + strow) * Ff + stcf;
  const ushort* Bsrc0 = Bt + (size_t)(n0 + strow) * Ff + ((sc ^ sx) * 8);
  const ushort* Bsrc1 = Bt + (size_t)(n0 + 64 + strow) * Ff + ((sc ^ sx) * 8);
  const int dstA0 = strow * 32 + ((sc ^ sx) * 8);         // SWIZZLED ds_write slot
  const int dstA1 = (64 + strow) * 32 + ((sc ^ sx) * 8);
  const int dstB0 = strow * 32 + sc * 8;                  // linear gload dst (= base + lane*16B)
  const int dstB1 = (64 + strow) * 32 + sc * 8;

  float4 rA0a, rA0b, rA1a, rA1b;  // staged A for next tile (2 rows x 8 f32)
  auto loadA = [&](int t) {
    const float* p0 = Asrc0 + t * 32;
    const float* p1 = Asrc1 + t * 32;
    rA0a = *(const float4*)p0; rA0b = *(const float4*)(p0 + 4);
    rA1a = *(const float4*)p1; rA1b = *(const float4*)(p1 + 4);
  };
  auto writeA = [&](int slot) {
    *(s16x8*)(Ads[slot] + dstA0) = pack8(rA0a, rA0b);
    *(s16x8*)(Ads[slot] + dstA1) = pack8(rA1a, rA1b);
  };
  auto stageB = [&](int t, int slot) {
    const int k0 = t * 32;
    gload16(Bsrc0 + k0, Bds[slot] + dstB0);
    gload16(Bsrc1 + k0, Bds[slot] + dstB1);
  };

  f32x4 acc[4][4];
#pragma unroll
  for (int m = 0; m < 4; m++)
#pragma unroll
    for (int n = 0; n < 4; n++) acc[m][n] = (f32x4){0.f, 0.f, 0.f, 0.f};

  // prologue: A(0) regs -> LDS slot0 (compiler-waited); then A(1) regs; B(0),B(1) gloads.
  loadA(0);
  writeA(0);
  stageB(0, 0);   // older than the 6 newest below -> drained by first wait_vm6
  loadA(1);       // 4 loads
  stageB(1, 1);   // 2 gloads  => newest 6 = A(1)x4 + B(1)x2

  int rs = 0, ps = 1, ws = 2;
  for (int t = 0; t < 32; ++t) {
    if (t < 31) wait_vm6(); else wait_vm0();  // drains B(t) + older; leaves A(t+1),B(t+1)
    wait_lgkm0();                             // publish last iter's A ds_writes
    __builtin_amdgcn_s_barrier();
    __builtin_amdgcn_sched_barrier(0);
    if (t < 31) writeA(ps);                   // A(t+1) regs -> slot (t+1)%3 (auto-waited)
    if (t < 30) { loadA(t + 2); stageB(t + 2, ws); }  // exactly 6 VM ops
    const ushort* As = Ads[rs];
    const ushort* Bs = Bds[rs];
    s16x8 af[4], bf[4];
#pragma unroll
    for (int m = 0; m < 4; m++) {
      const int ra = wr * 64 + m * 16 + ln;
      af[m] = *(const s16x8*)(As + ra * 32 + ((g ^ ((ra >> 1) & 3)) * 8));
    }
#pragma unroll
    for (int n = 0; n < 4; n++) {
      const int rb = wc * 64 + n * 16 + ln;
      bf[n] = *(const s16x8*)(Bs + rb * 32 + ((g ^ ((rb >> 1) & 3)) * 8));
    }
    __builtin_amdgcn_s_setprio(1);
#pragma unroll
    for (int m = 0; m < 4; m++)
#pragma unroll
      for (int n = 0; n < 4; n++)
        acc[m][n] = __builtin_amdgcn_mfma_f32_16x16x32_bf16(af[m], bf[n], acc[m][n], 0, 0, 0);
    __builtin_amdgcn_s_setprio(0);
    rs = rs == 2 ? 0 : rs + 1;
    ps = ps == 2 ? 0 : ps + 1;
    ws = ws == 2 ? 0 : ws + 1;
  }
#pragma unroll
  for (int m = 0; m < 4; m++) {
    const int r0 = m0 + wr * 64 + m * 16 + g * 4;
#pragma unroll
    for (int n = 0; n < 4; n++) {
      const int col = n0 + wc * 64 + n * 16 + ln;
      const float bv = bias[col];
      if (mode == 2) {
        // V-fragment store: batch bb, row-in-batch rb, pi^-1 on kv within 64-block
        const int bb = r0 >> 11, rb = r0 & 2047;
        const int x = rb & 63;
        const int pbase = (x & 0x20) | ((x & 0x0C) << 1) | ((x & 0x10) >> 2);
        s16x4 o4;
#pragma unroll
        for (int r = 0; r < 4; r++) o4[r] = (short)f2bf(acc[m][n][r] + bv);
        *(s16x4*)((ushort*)Cout + ((size_t)bb * Ff + col) * Tt + (rb & ~63) + pbase) = o4;
      } else {
#pragma unroll
        for (int r = 0; r < 4; r++)
          ((ushort*)Cout)[(size_t)(r0 + r) * Ff + col] = f2bf((acc[m][n][r] + bv) * scale);
      }
    }
  }
}

__global__ __launch_bounds__(256) void qkv_gemm_kernel(
    const float* __restrict__ Xq, const float* __restrict__ Xk, const float* __restrict__ Xv,
    const ushort* __restrict__ Wqt, const ushort* __restrict__ Wkt, const ushort* __restrict__ Wvt,
    const float* __restrict__ bq, const float* __restrict__ bk, const float* __restrict__ bv,
    ushort* __restrict__ Qb, ushort* __restrict__ Kb, ushort* __restrict__ Vpt) {
  // T1: XCD-chunked bijective block swizzle (768 blocks -> 96 contiguous per XCD)
  const int lin = blockIdx.x + 8 * blockIdx.y + 256 * blockIdx.z;
  const int work = (lin & 7) * 96 + (lin >> 3);
  const int z = work >> 8;
  const int r = work & 255;
  const int m0 = (r >> 3) * 128, n0 = (r & 7) * 128;
  const float* A = z == 0 ? Xq : (z == 1 ? Xk : Xv);
  const ushort* Wt = z == 0 ? Wqt : (z == 1 ? Wkt : Wvt);
  const float* bias = z == 0 ? bq : (z == 1 ? bk : bv);
  void* C = z == 0 ? (void*)Qb : (z == 1 ? (void*)Kb : (void*)Vpt);
  const float scale = z == 0 ? 0.125f * LOG2E : 1.0f;  // fold 1/sqrt(64) and log2(e) into Q
  gemm_core_f32a(A, Wt, bias, C, scale, z == 2 ? 2 : 1, m0, n0);
}

__global__ __launch_bounds__(256) void out_gemm_kernel(const ushort* __restrict__ AO,
                                                       const ushort* __restrict__ Wot,
                                                       const float* __restrict__ bo,
                                                       float* __restrict__ Out) {
  // T1: XCD-chunked bijective block swizzle (512 blocks -> 64 contiguous per XCD)
  const int lin = blockIdx.x + 8 * blockIdx.y;
  const int work = (lin & 7) * 64 + (lin >> 3);
  const int m0 = (work >> 3) * 64, n0 = (work & 7) * 128;  // 64x128 tiles
  gemm_core64(AO, Wot, bo, Out, m0, n0);
}

// ---------------- flash attention (round-8 best: max-free exp2, QBLK=128, ring-4 pair sync) ----------------
// grid (qb=16, h=16, b=2), 256 thr (4 waves). BQ=128 (two 16-row groups/wave), BK=64, D=64.
// Ring-4 (64 KB LDS): per half-iter {compute 2 tiles -> __syncthreads -> stage next pair};
// each staged pair gets a full 2-tile compute phase to land; 16 barriers total.
// l on MFMA pipe via ones-B trick (acc reg r = l for q-row 4g+r).
__global__ __launch_bounds__(256) void flash_kernel(
    const ushort* __restrict__ Qb, const ushort* __restrict__ Kb, const ushort* __restrict__ Vpt,
    const int* __restrict__ flags, const int* __restrict__ mask, ushort* __restrict__ AO) {
  __shared__ ushort Ks[4][64 * 64];
  __shared__ ushort Vs[4][64 * 64];
  // T1: XCD-chunked bijective block swizzle (512 blocks -> 64 per XCD = 4 heads' KV, L2-fit)
  const int lin = blockIdx.x + 16 * (blockIdx.y + 16 * blockIdx.z);
  const int work = (lin & 7) * 64 + (lin >> 3);
  const int qb = work & 15, h = (work >> 4) & 15, b = work >> 8;
  const int tid = threadIdx.x, lane = tid & 63, w = tid >> 6;
  const int g = lane >> 4, ln = lane & 15;

  const ushort* Qg = Qb + ((size_t)b * Tt + qb * 128) * Ff + h * Dk;
  const ushort* Kg = Kb + ((size_t)b * Tt) * Ff + h * Dk;
  const ushort* Vg = Vpt + (size_t)(b * Ff + h * Dk) * Tt;  // rows d, stride Tt, cols pi-ordered

  const int srow = lane >> 3;
  const int swzch = ((lane & 7) ^ srow) * 8;  // inverse-swizzled source chunk (128B rows need XOR)

  // persistent staging source pointers (advance one PAIR of KV tiles per stage2)
  const ushort* ksrc0 = Kg + (size_t)(w * 16 + srow) * Ff + swzch;
  const ushort* ksrc1 = ksrc0 + (size_t)8 * Ff;
  const ushort* vsrc0 = Vg + (size_t)(w * 16 + srow) * Tt + swzch;
  const ushort* vsrc1 = vsrc0 + (size_t)8 * Tt;

  // Q fragments DIRECT from global (one-time read): qf{j}[c] = Q[j*64 + w*16+ln][c*32+g*8 ..+7]
  s16x8 qf0[2], qf1[2];
  {
    const ushort* Qrow0 = Qg + (size_t)(w * 16 + ln) * Ff;
    const ushort* Qrow1 = Qrow0 + (size_t)64 * Ff;
    qf0[0] = *(const s16x8*)(Qrow0 + g * 8);
    qf0[1] = *(const s16x8*)(Qrow0 + 32 + g * 8);
    qf1[0] = *(const s16x8*)(Qrow1 + g * 8);
    qf1[1] = *(const s16x8*)(Qrow1 + 32 + g * 8);
  }
  const int* flagrow0 = flags + (b * 32 + qb * 2) * 32;
  const int f0 = (lane < 32) ? flagrow0[lane] : 1;
  const int f1 = (lane < 32) ? flagrow0[32 + lane] : 1;

  // stage a PAIR of consecutive KV tiles into two slots, advance pointers by 2 tiles
  auto stage2 = [&](ushort* Kd0, ushort* Vd0, ushort* Kd1, ushort* Vd1) {
    const int r0 = w * 16;
    gload16(ksrc0, Kd0 + r0 * 64);
    gload16(ksrc1, Kd0 + (r0 + 8) * 64);
    gload16(vsrc0, Vd0 + r0 * 64);
    gload16(vsrc1, Vd0 + (r0 + 8) * 64);
    gload16(ksrc0 + (size_t)64 * Ff, Kd1 + r0 * 64);
    gload16(ksrc1 + (size_t)64 * Ff, Kd1 + (r0 + 8) * 64);
    gload16(vsrc0 + 64, Vd1 + r0 * 64);
    gload16(vsrc1 + 64, Vd1 + (r0 + 8) * 64);
    ksrc0 += (size_t)128 * Ff; ksrc1 += (size_t)128 * Ff;
    vsrc0 += 128; vsrc1 += 128;
  };

  // prologue: stage tiles 0..3 into slots 0..3, full drain once
  stage2(Ks[0], Vs[0], Ks[1], Vs[1]);
  stage2(Ks[2], Vs[2], Ks[3], Vs[3]);
  __syncthreads();
  const unsigned long long bm0 = __ballot(f0 == 0);
  const unsigned long long bm1 = __ballot(f1 == 0);

  // hoisted LDS read byte-offsets: rows i*16+ln, chunk c — shared by QK (K) and PV (V) reads
  int loff[4][2];
#pragma unroll
  for (int i = 0; i < 4; i++)
#pragma unroll
    for (int c = 0; c < 2; c++) {
      const int row = i * 16 + ln;
      loff[i][c] = row * 128 + ((c * 64 + g * 16) ^ ((row & 7) << 4));
    }
  const char* Kbase = (const char*)&Ks[0][0];
  const char* Vbase = (const char*)&Vs[0][0];

  s16x8 onesf;
#pragma unroll
  for (int j = 0; j < 8; ++j) onesf[j] = (short)0x3F80;  // bf16 1.0

  f32x4 accl0 = (f32x4){0.f, 0.f, 0.f, 0.f}, accl1 = (f32x4){0.f, 0.f, 0.f, 0.f};
  f32x4 o0[4], o1[4];
#pragma unroll
  for (int ds = 0; ds < 4; ds++) { o0[ds] = (f32x4){0.f, 0.f, 0.f, 0.f}; o1[ds] = (f32x4){0.f, 0.f, 0.f, 0.f}; }

  auto body = [&](int slot, int kt) {
    const char* Kc = Kbase + slot * 8192;
    const char* Vc = Vbase + slot * 8192;
    // --- S'^T = K * Q^T (log2 domain); each kf feeds BOTH q-groups ---
    f32x4 sf0[4], sf1[4];
    __builtin_amdgcn_s_setprio(1);
#pragma unroll
    for (int ks = 0; ks < 4; ++ks) {
      f32x4 a0 = (f32x4){0.f, 0.f, 0.f, 0.f};
      f32x4 a1 = (f32x4){0.f, 0.f, 0.f, 0.f};
#pragma unroll
      for (int c = 0; c < 2; c++) {
        const s16x8 kf = *(const s16x8*)(Kc + loff[ks][c]);
        a0 = __builtin_amdgcn_mfma_f32_16x16x32_bf16(kf, qf0[c], a0, 0, 0, 0);
        a1 = __builtin_amdgcn_mfma_f32_16x16x32_bf16(kf, qf1[c], a1, 0, 0, 0);
      }
      sf0[ks] = a0; sf1[ks] = a1;
    }
    __builtin_amdgcn_s_setprio(0);
    // --- mask (skipped for all-positive tiles); masked scores -> -10000 -> exp2 -> 0 ---
    if ((bm0 >> kt) & 1ull) {
      const int qg_ = qb * 128 + w * 16 + ln;
#pragma unroll
      for (int ks = 0; ks < 4; ++ks) {
        const int4 mv = *(const int4*)(mask + ((size_t)b * Tt + qg_) * Tt + kt * 64 + ks * 16 + g * 4);
        if (mv.x <= 0) sf0[ks][0] = -10000.f;
        if (mv.y <= 0) sf0[ks][1] = -10000.f;
        if (mv.z <= 0) sf0[ks][2] = -10000.f;
        if (mv.w <= 0) sf0[ks][3] = -10000.f;
      }
    }
    if ((bm1 >> kt) & 1ull) {
      const int qg_ = qb * 128 + 64 + w * 16 + ln;
#pragma unroll
      for (int ks = 0; ks < 4; ++ks) {
        const int4 mv = *(const int4*)(mask + ((size_t)b * Tt + qg_) * Tt + kt * 64 + ks * 16 + g * 4);
        if (mv.x <= 0) sf1[ks][0] = -10000.f;
        if (mv.y <= 0) sf1[ks][1] = -10000.f;
        if (mv.z <= 0) sf1[ks][2] = -10000.f;
        if (mv.w <= 0) sf1[ks][3] = -10000.f;
      }
    }
    // --- raw exp2 (no max subtraction) ---
#pragma unroll
    for (int ks = 0; ks < 4; ++ks) {
#pragma unroll
      for (int r = 0; r < 4; ++r) {
        sf0[ks][r] = __builtin_amdgcn_exp2f(sf0[ks][r]);
        sf1[ks][r] = __builtin_amdgcn_exp2f(sf1[ks][r]);
      }
    }
    // --- pack P A-frags via v_cvt_pk: word w of pa{j}[c] = slots (2w,2w+1), i=4f+r ---
    i32x4 paw0[2], paw1[2];
#pragma unroll
    for (int c = 0; c < 2; c++)
#pragma unroll
      for (int f = 0; f < 2; f++)
#pragma unroll
        for (int hh = 0; hh < 2; hh++) {
          paw0[c][f * 2 + hh] = cvt_pk_bf16(sf0[2 * c + f][2 * hh], sf0[2 * c + f][2 * hh + 1]);
          paw1[c][f * 2 + hh] = cvt_pk_bf16(sf1[2 * c + f][2 * hh], sf1[2 * c + f][2 * hh + 1]);
        }
    const s16x8 pa00 = __builtin_bit_cast(s16x8, paw0[0]);
    const s16x8 pa01 = __builtin_bit_cast(s16x8, paw0[1]);
    const s16x8 pa10 = __builtin_bit_cast(s16x8, paw1[0]);
    const s16x8 pa11 = __builtin_bit_cast(s16x8, paw1[1]);
    // --- PV + l on MFMA pipe: l partial = mfma(pa, ones) (every out col = row sum) ---
    __builtin_amdgcn_s_setprio(1);
    accl0 = __builtin_amdgcn_mfma_f32_16x16x32_bf16(pa00, onesf, accl0, 0, 0, 0);
    accl0 = __builtin_amdgcn_mfma_f32_16x16x32_bf16(pa01, onesf, accl0, 0, 0, 0);
    accl1 = __builtin_amdgcn_mfma_f32_16x16x32_bf16(pa10, onesf, accl1, 0, 0, 0);
    accl1 = __builtin_amdgcn_mfma_f32_16x16x32_bf16(pa11, onesf, accl1, 0, 0, 0);
#pragma unroll
    for (int ds = 0; ds < 4; ++ds) {
#pragma unroll
      for (int c = 0; c < 2; ++c) {
        const s16x8 vf = *(const s16x8*)(Vc + loff[ds][c]);
        o0[ds] = __builtin_amdgcn_mfma_f32_16x16x32_bf16(c == 0 ? pa00 : pa01, vf, o0[ds], 0, 0, 0);
        o1[ds] = __builtin_amdgcn_mfma_f32_16x16x32_bf16(c == 0 ? pa10 : pa11, vf, o1[ds], 0, 0, 0);
      }
    }
    __builtin_amdgcn_s_setprio(0);
  };

  // main loop: 16 barriers; each stage issued right after a barrier, drained by the NEXT one
  for (int kt = 0; kt < 32; kt += 4) {
    body(0, kt);
    body(1, kt + 1);
    __syncthreads();
    if (kt + 4 < 32) stage2(Ks[0], Vs[0], Ks[1], Vs[1]);
    body(2, kt + 2);
    body(3, kt + 3);
    __syncthreads();
    if (kt + 6 < 32) stage2(Ks[2], Vs[2], Ks[3], Vs[3]);
  }

  // --- epilogue: l already per-row in accl (no shuffles), normalize, store bf16 ---
  float inv0[4], inv1[4];
#pragma unroll
  for (int r = 0; r < 4; ++r) {
    inv0[r] = 1.0f / accl0[r];
    inv1[r] = 1.0f / accl1[r];
  }
  ushort* AOg0 = AO + ((size_t)b * Tt + qb * 128 + w * 16) * Ff + h * Dk;
  ushort* AOg1 = AOg0 + (size_t)64 * Ff;
#pragma unroll
  for (int ds = 0; ds < 4; ++ds)
#pragma unroll
    for (int r = 0; r < 4; ++r) {
      AOg0[(size_t)(g * 4 + r) * Ff + ds * 16 + ln] = f2bf(o0[ds][r] * inv0[r]);
      AOg1[(size_t)(g * 4 + r) * Ff + ds * 16 + ln] = f2bf(o1[ds][r] * inv1[r]);
    }
}

// ---------------- host launch ----------------
extern "C" void kernel_launch(void* const* d_in, const int* in_sizes, int n_in,
                              void* d_out, int out_size, void* d_ws, size_t ws_size,
                              hipStream_t stream) {
  const float* query = (const float*)d_in[0];
  const float* key_  = (const float*)d_in[1];
  const float* value = (const float*)d_in[2];
  const int*   mask  = (const int*)d_in[3];
  const float* Wq = (const float*)d_in[4];  const float* bq = (const float*)d_in[5];
  const float* Wk = (const float*)d_in[6];  const float* bk = (const float*)d_in[7];
  const float* Wv = (const float*)d_in[8];  const float* bv = (const float*)d_in[9];
  const float* Wo = (const float*)d_in[10]; const float* bo = (const float*)d_in[11];
  float* Out = (float*)d_out;

  constexpr size_t SZ_X = (size_t)Mm * Ff * 2;  // 8 MB bf16 matrix
  constexpr size_t SZ_W = (size_t)Ff * Ff * 2;  // 2 MB bf16 weight
  uintptr_t p = (uintptr_t)d_ws;
  auto alloc = [&](size_t sz) { void* r = (void*)p; p += (sz + 255) & ~(size_t)255; return r; };
  ushort* AO  = (ushort*)alloc(SZ_X);  // flash output
  ushort* Wqt = (ushort*)alloc(SZ_W);
  ushort* Wkt = (ushort*)alloc(SZ_W);
  ushort* Wvt = (ushort*)alloc(SZ_W);
  ushort* Wot = (ushort*)alloc(SZ_W);
  ushort* Qp  = (ushort*)alloc(SZ_X);
  ushort* Kp  = (ushort*)alloc(SZ_X);
  ushort* Vpt = (ushort*)alloc(SZ_X);  // [b][d][kv], pi-ordered columns, written by qkv_gemm z=2
  int* flags = (int*)alloc((size_t)Bb * 32 * 32 * 4);

  prep_kernel<<<dim3(3072), 256, 0, stream>>>(Wq, Wk, Wv, Wo, Wqt, Wkt, Wvt, Wot, mask, flags);
  qkv_gemm_kernel<<<dim3(8, 32, 3), 256, 0, stream>>>(query, key_, value, Wqt, Wkt, Wvt,
                                                      bq, bk, bv, Qp, Kp, Vpt);
  flash_kernel<<<dim3(16, 16, 2), 256, 0, stream>>>(Qp, Kp, Vpt, flags, mask, AO);
  out_gemm_kernel<<<dim3(8, 64), 256, 0, stream>>>(AO, Wot, bo, Out);
}